// Round 1
// baseline (95.294 us; speedup 1.0000x reference)
//
#include <hip/hip_runtime.h>

// Problem constants
constexpr int Bn = 4, Ln = 512, Mn = 32, EMBn = 512, Hn = 8, HSn = 64;
constexpr int Rn = Mn * Hn; // 256 (row index r = m*H + h)

__device__ __forceinline__ float wave_sum(float v) {
#pragma unroll
  for (int off = 1; off < 64; off <<= 1) v += __shfl_xor(v, off, 64);
  return v;
}
__device__ __forceinline__ float wave_max(float v) {
#pragma unroll
  for (int off = 1; off < 64; off <<= 1) v = fmaxf(v, __shfl_xor(v, off, 64));
  return v;
}

// K1: LayerNorm. One wave per row of 512. grid = B*L/4, block = 256.
__global__ __launch_bounds__(256) void ln_kernel(
    const float* __restrict__ x, const float* __restrict__ gam,
    const float* __restrict__ bet, float* __restrict__ hbuf) {
  int row = blockIdx.x * 4 + (threadIdx.x >> 6);
  int lane = threadIdx.x & 63;
  const float* xr = x + (size_t)row * EMBn + lane * 8;
  float4 a0 = *(const float4*)xr;
  float4 a1 = *(const float4*)(xr + 4);
  float s = a0.x + a0.y + a0.z + a0.w + a1.x + a1.y + a1.z + a1.w;
  float ss = a0.x * a0.x + a0.y * a0.y + a0.z * a0.z + a0.w * a0.w +
             a1.x * a1.x + a1.y * a1.y + a1.z * a1.z + a1.w * a1.w;
  s = wave_sum(s);
  ss = wave_sum(ss);
  float mu = s * (1.0f / EMBn);
  float var = ss * (1.0f / EMBn) - mu * mu;
  float rstd = rsqrtf(var + 1e-5f);
  const float* gp = gam + lane * 8;
  const float* bp = bet + lane * 8;
  float4 g0 = *(const float4*)gp, g1 = *(const float4*)(gp + 4);
  float4 b0 = *(const float4*)bp, b1 = *(const float4*)(bp + 4);
  float4 o0, o1;
  o0.x = (a0.x - mu) * rstd * g0.x + b0.x;
  o0.y = (a0.y - mu) * rstd * g0.y + b0.y;
  o0.z = (a0.z - mu) * rstd * g0.z + b0.z;
  o0.w = (a0.w - mu) * rstd * g0.w + b0.w;
  o1.x = (a1.x - mu) * rstd * g1.x + b1.x;
  o1.y = (a1.y - mu) * rstd * g1.y + b1.y;
  o1.z = (a1.z - mu) * rstd * g1.z + b1.z;
  o1.w = (a1.w - mu) * rstd * g1.w + b1.w;
  float* hp = hbuf + (size_t)row * EMBn + lane * 8;
  *(float4*)hp = o0;
  *(float4*)(hp + 4) = o1;
}

// K2: P[r,e] = sum_s cells[m,h,s]*q_w[h*64+s, e]; pb[r] = sum_s cells*q_b.
// grid = R (=256 blocks, one per (m,h)), block = 256.
__global__ __launch_bounds__(256) void pproj_kernel(
    const float* __restrict__ cells, const float* __restrict__ q_w,
    const float* __restrict__ q_b, float* __restrict__ P,
    float* __restrict__ pb) {
  int r = blockIdx.x;
  int m = r >> 3, hh = r & 7;
  __shared__ float cs[HSn];
  int tid = threadIdx.x;
  if (tid < HSn) cs[tid] = cells[(size_t)(m * Hn + hh) * HSn + tid];
  __syncthreads();
  for (int e = tid; e < EMBn; e += 256) {
    float acc = 0.f;
#pragma unroll 8
    for (int s2 = 0; s2 < HSn; ++s2)
      acc += cs[s2] * q_w[(size_t)(hh * HSn + s2) * EMBn + e];
    P[(size_t)r * EMBn + e] = acc;
  }
  if (tid == 0) {
    float acc = 0.f;
    for (int s2 = 0; s2 < HSn; ++s2) acc += cs[s2] * q_b[hh * HSn + s2];
    pb[r] = acc;
  }
}

// K3: logits S[b,r,l] = (sum_e P[r,e]*h[b,l,e] + pb[r]) * HS^-0.5
// tile: 32 r x 64 l, K-chunks of 64. grid = (L/64, R/32, B), block = 256.
__global__ __launch_bounds__(256) void score_kernel(
    const float* __restrict__ P, const float* __restrict__ pb,
    const float* __restrict__ hbuf, float* __restrict__ S) {
  int b = blockIdx.z;
  int r0 = blockIdx.y * 32;
  int l0 = blockIdx.x * 64;
  __shared__ float Ps[32][65];
  __shared__ float hs[64][65];
  int tid = threadIdx.x;
  int ty = tid >> 4, tx = tid & 15;
  int tx4 = tx << 2;
  float acc00 = 0, acc01 = 0, acc02 = 0, acc03 = 0;
  float acc10 = 0, acc11 = 0, acc12 = 0, acc13 = 0;
  for (int ek = 0; ek < EMBn; ek += 64) {
#pragma unroll
    for (int i = 0; i < 2; ++i) {
      int fi = tid + i * 256;
      int row = fi >> 4;
      int c4 = (fi & 15) << 2;
      float4 t = *(const float4*)&P[(size_t)(r0 + row) * EMBn + ek + c4];
      Ps[row][c4] = t.x; Ps[row][c4 + 1] = t.y;
      Ps[row][c4 + 2] = t.z; Ps[row][c4 + 3] = t.w;
    }
#pragma unroll
    for (int i = 0; i < 4; ++i) {
      int fi = tid + i * 256;
      int row = fi >> 4;
      int c4 = (fi & 15) << 2;
      float4 t = *(const float4*)&hbuf[((size_t)b * Ln + l0 + row) * EMBn + ek + c4];
      hs[row][c4] = t.x; hs[row][c4 + 1] = t.y;
      hs[row][c4 + 2] = t.z; hs[row][c4 + 3] = t.w;
    }
    __syncthreads();
#pragma unroll 8
    for (int e = 0; e < 64; ++e) {
      float a0 = Ps[ty][e];
      float a1 = Ps[ty + 16][e];
      float v0 = hs[tx4 + 0][e];
      float v1 = hs[tx4 + 1][e];
      float v2 = hs[tx4 + 2][e];
      float v3 = hs[tx4 + 3][e];
      acc00 += a0 * v0; acc01 += a0 * v1; acc02 += a0 * v2; acc03 += a0 * v3;
      acc10 += a1 * v0; acc11 += a1 * v1; acc12 += a1 * v2; acc13 += a1 * v3;
    }
    __syncthreads();
  }
  const float sc = 0.125f; // HS^-0.5
  {
    int r = r0 + ty;
    float pbv = pb[r];
    float4 o = make_float4((acc00 + pbv) * sc, (acc01 + pbv) * sc,
                           (acc02 + pbv) * sc, (acc03 + pbv) * sc);
    *(float4*)&S[((size_t)b * Rn + r) * Ln + l0 + tx4] = o;
  }
  {
    int r = r0 + ty + 16;
    float pbv = pb[r];
    float4 o = make_float4((acc10 + pbv) * sc, (acc11 + pbv) * sc,
                           (acc12 + pbv) * sc, (acc13 + pbv) * sc);
    *(float4*)&S[((size_t)b * Rn + r) * Ln + l0 + tx4] = o;
  }
}

// K4: softmax over l (512) per row, in place. One wave per row.
// grid = B*R/4, block = 256.
__global__ __launch_bounds__(256) void softmax_kernel(float* __restrict__ S) {
  int row = blockIdx.x * 4 + (threadIdx.x >> 6);
  int lane = threadIdx.x & 63;
  float* sr = S + (size_t)row * Ln + lane * 8;
  float4 a0 = *(float4*)sr;
  float4 a1 = *(float4*)(sr + 4);
  float mx = fmaxf(fmaxf(fmaxf(a0.x, a0.y), fmaxf(a0.z, a0.w)),
                   fmaxf(fmaxf(a1.x, a1.y), fmaxf(a1.z, a1.w)));
  mx = wave_max(mx);
  a0.x = __expf(a0.x - mx); a0.y = __expf(a0.y - mx);
  a0.z = __expf(a0.z - mx); a0.w = __expf(a0.w - mx);
  a1.x = __expf(a1.x - mx); a1.y = __expf(a1.y - mx);
  a1.z = __expf(a1.z - mx); a1.w = __expf(a1.w - mx);
  float s = a0.x + a0.y + a0.z + a0.w + a1.x + a1.y + a1.z + a1.w;
  s = wave_sum(s);
  float inv = 1.0f / s;
  a0.x *= inv; a0.y *= inv; a0.z *= inv; a0.w *= inv;
  a1.x *= inv; a1.y *= inv; a1.z *= inv; a1.w *= inv;
  *(float4*)sr = a0;
  *(float4*)(sr + 4) = a1;
}

// K5: G[b,r,j] = sum_l W[b,r,l]*h[b,l,j]. Same tiling as K3 (NN layout).
// grid = (EMB/64, R/32, B), block = 256.
__global__ __launch_bounds__(256) void gmat_kernel(
    const float* __restrict__ W, const float* __restrict__ hbuf,
    float* __restrict__ G) {
  int b = blockIdx.z;
  int r0 = blockIdx.y * 32;
  int j0 = blockIdx.x * 64;
  __shared__ float Ws[32][65];
  __shared__ float hs[64][65];
  int tid = threadIdx.x;
  int ty = tid >> 4, tx = tid & 15;
  int tx4 = tx << 2;
  float acc00 = 0, acc01 = 0, acc02 = 0, acc03 = 0;
  float acc10 = 0, acc11 = 0, acc12 = 0, acc13 = 0;
  for (int lk = 0; lk < Ln; lk += 64) {
#pragma unroll
    for (int i = 0; i < 2; ++i) {
      int fi = tid + i * 256;
      int row = fi >> 4;
      int c4 = (fi & 15) << 2;
      float4 t = *(const float4*)&W[((size_t)b * Rn + r0 + row) * Ln + lk + c4];
      Ws[row][c4] = t.x; Ws[row][c4 + 1] = t.y;
      Ws[row][c4 + 2] = t.z; Ws[row][c4 + 3] = t.w;
    }
#pragma unroll
    for (int i = 0; i < 4; ++i) {
      int fi = tid + i * 256;
      int row = fi >> 4;
      int c4 = (fi & 15) << 2;
      float4 t = *(const float4*)&hbuf[((size_t)b * Ln + lk + row) * EMBn + j0 + c4];
      hs[row][c4] = t.x; hs[row][c4 + 1] = t.y;
      hs[row][c4 + 2] = t.z; hs[row][c4 + 3] = t.w;
    }
    __syncthreads();
#pragma unroll 8
    for (int l = 0; l < 64; ++l) {
      float a0 = Ws[ty][l];
      float a1 = Ws[ty + 16][l];
      float v0 = hs[l][tx4 + 0];
      float v1 = hs[l][tx4 + 1];
      float v2 = hs[l][tx4 + 2];
      float v3 = hs[l][tx4 + 3];
      acc00 += a0 * v0; acc01 += a0 * v1; acc02 += a0 * v2; acc03 += a0 * v3;
      acc10 += a1 * v0; acc11 += a1 * v1; acc12 += a1 * v2; acc13 += a1 * v3;
    }
    __syncthreads();
  }
  {
    int r = r0 + ty;
    *(float4*)&G[((size_t)b * Rn + r) * EMBn + j0 + tx4] =
        make_float4(acc00, acc01, acc02, acc03);
  }
  {
    int r = r0 + ty + 16;
    *(float4*)&G[((size_t)b * Rn + r) * EMBn + j0 + tx4] =
        make_float4(acc10, acc11, acc12, acc13);
  }
}

// K6: out[b, (m,h), s] = dot(v[m, h*64+s, :], G[b, r(m,h), :]) + vb[m, h*64+s]
// Output flat index = ((b*H + h)*M + m)*HS + s  (torch-faithful reshape).
// grid = R (one block per (m,h)), block = 256 (4 waves; wave per v-row).
__global__ __launch_bounds__(256) void out_kernel(
    const float* __restrict__ v, const float* __restrict__ vb,
    const float* __restrict__ G, float* __restrict__ out) {
  int bid = blockIdx.x; // r = m*H + hh
  int m = bid >> 3, hh = bid & 7;
  __shared__ float Gs[Bn][EMBn]; // 8 KiB
  int tid = threadIdx.x;
#pragma unroll
  for (int i = 0; i < 8; ++i) {
    int idx = tid + i * 256;
    int bb = idx >> 9, e = idx & 511;
    Gs[bb][e] = G[((size_t)bb * Rn + bid) * EMBn + e];
  }
  __syncthreads();
  int wid = tid >> 6, lane = tid & 63;
  for (int rr = wid; rr < HSn; rr += 4) {
    const float* vr = v + ((size_t)m * EMBn + hh * HSn + rr) * EMBn + lane * 8;
    float4 v0 = *(const float4*)vr;
    float4 v1 = *(const float4*)(vr + 4);
    float acc[Bn];
#pragma unroll
    for (int bb = 0; bb < Bn; ++bb) {
      const float* gp = &Gs[bb][lane * 8];
      float4 g0 = *(const float4*)gp;
      float4 g1 = *(const float4*)(gp + 4);
      acc[bb] = v0.x * g0.x + v0.y * g0.y + v0.z * g0.z + v0.w * g0.w +
                v1.x * g1.x + v1.y * g1.y + v1.z * g1.z + v1.w * g1.w;
    }
#pragma unroll
    for (int off = 1; off < 64; off <<= 1) {
#pragma unroll
      for (int bb = 0; bb < Bn; ++bb) acc[bb] += __shfl_xor(acc[bb], off, 64);
    }
    if (lane == 0) {
      float vbv = vb[(size_t)m * EMBn + hh * HSn + rr];
#pragma unroll
      for (int bb = 0; bb < Bn; ++bb) {
        out[(((size_t)bb * Hn + hh) * Mn + m) * HSn + rr] = acc[bb] + vbv;
      }
    }
  }
}

extern "C" void kernel_launch(void* const* d_in, const int* in_sizes, int n_in,
                              void* d_out, int out_size, void* d_ws,
                              size_t ws_size, hipStream_t stream) {
  const float* x = (const float*)d_in[0];
  const float* cells = (const float*)d_in[1];
  const float* q_w = (const float*)d_in[2];
  const float* q_b = (const float*)d_in[3];
  const float* v = (const float*)d_in[4];
  const float* vb = (const float*)d_in[5];
  const float* ln_g = (const float*)d_in[6];
  const float* ln_b = (const float*)d_in[7];
  float* out = (float*)d_out;

  float* ws = (float*)d_ws;
  float* hbuf = ws;                            // B*L*EMB       = 1,048,576 f
  float* P = hbuf + (size_t)Bn * Ln * EMBn;    // R*EMB         =   131,072 f
  float* pb = P + (size_t)Rn * EMBn;           // R             =       256 f
  float* S = pb + Rn;                          // B*R*L         =   524,288 f
  float* G = S + (size_t)Bn * Rn * Ln;         // B*R*EMB       =   524,288 f
  // total ~8.9 MB of d_ws

  ln_kernel<<<Bn * Ln / 4, 256, 0, stream>>>(x, ln_g, ln_b, hbuf);
  pproj_kernel<<<Rn, 256, 0, stream>>>(cells, q_w, q_b, P, pb);
  dim3 g3(Ln / 64, Rn / 32, Bn);
  score_kernel<<<g3, 256, 0, stream>>>(P, pb, hbuf, S);
  softmax_kernel<<<Bn * Rn / 4, 256, 0, stream>>>(S);
  dim3 g5(EMBn / 64, Rn / 32, Bn);
  gmat_kernel<<<g5, 256, 0, stream>>>(S, hbuf, G);
  out_kernel<<<Rn, 256, 0, stream>>>(v, vb, G, out);
}

// Round 2
// 43.081 us; speedup vs baseline: 2.2120x; 2.2120x over previous
//
#include <hip/hip_runtime.h>

typedef unsigned short u16;
typedef float f32x4 __attribute__((ext_vector_type(4)));
typedef short bf16x8 __attribute__((ext_vector_type(8)));

constexpr int Bn = 4, Ln = 512, Mn = 32, EMBn = 512, Hn = 8, HSn = 64;
constexpr int Rn = Mn * Hn; // 256

__device__ __forceinline__ float wave_sum(float v) {
#pragma unroll
  for (int off = 1; off < 64; off <<= 1) v += __shfl_xor(v, off, 64);
  return v;
}
__device__ __forceinline__ float wave_max(float v) {
#pragma unroll
  for (int off = 1; off < 64; off <<= 1) v = fmaxf(v, __shfl_xor(v, off, 64));
  return v;
}
__device__ __forceinline__ u16 f2bf(float f) {
  unsigned u = __float_as_uint(f);
  unsigned r = (u + 0x7FFFu + ((u >> 16) & 1u)) >> 16;
  return (u16)r;
}
__device__ __forceinline__ unsigned pack2(float a, float b) {
  return (unsigned)f2bf(a) | ((unsigned)f2bf(b) << 16);
}

// ---------------------------------------------------------------------------
// K_A: blocks [0,512): LayerNorm -> h_bf16. blocks [512,768): P = cells*q_w.
// ---------------------------------------------------------------------------
__global__ __launch_bounds__(256) void ln_pproj_kernel(
    const float* __restrict__ x, const float* __restrict__ gam,
    const float* __restrict__ bet, const float* __restrict__ cells,
    const float* __restrict__ q_w, const float* __restrict__ q_b,
    u16* __restrict__ hb, u16* __restrict__ Pb, float* __restrict__ pb) {
  int bid = blockIdx.x, tid = threadIdx.x;
  __shared__ float cs[HSn];
  if (bid < 512) {
    int row = bid * 4 + (tid >> 6), lane = tid & 63;
    const float* xr = x + (size_t)row * EMBn + lane * 8;
    float4 a0 = *(const float4*)xr;
    float4 a1 = *(const float4*)(xr + 4);
    float s = a0.x + a0.y + a0.z + a0.w + a1.x + a1.y + a1.z + a1.w;
    float ss = a0.x * a0.x + a0.y * a0.y + a0.z * a0.z + a0.w * a0.w +
               a1.x * a1.x + a1.y * a1.y + a1.z * a1.z + a1.w * a1.w;
    s = wave_sum(s);
    ss = wave_sum(ss);
    float mu = s * (1.0f / EMBn);
    float var = ss * (1.0f / EMBn) - mu * mu;
    float rstd = rsqrtf(var + 1e-5f);
    const float* gp = gam + lane * 8;
    const float* bp = bet + lane * 8;
    float4 g0 = *(const float4*)gp, g1 = *(const float4*)(gp + 4);
    float4 b0 = *(const float4*)bp, b1 = *(const float4*)(bp + 4);
    float4 o0, o1;
    o0.x = (a0.x - mu) * rstd * g0.x + b0.x;
    o0.y = (a0.y - mu) * rstd * g0.y + b0.y;
    o0.z = (a0.z - mu) * rstd * g0.z + b0.z;
    o0.w = (a0.w - mu) * rstd * g0.w + b0.w;
    o1.x = (a1.x - mu) * rstd * g1.x + b1.x;
    o1.y = (a1.y - mu) * rstd * g1.y + b1.y;
    o1.z = (a1.z - mu) * rstd * g1.z + b1.z;
    o1.w = (a1.w - mu) * rstd * g1.w + b1.w;
    uint4 st;
    st.x = pack2(o0.x, o0.y);
    st.y = pack2(o0.z, o0.w);
    st.z = pack2(o1.x, o1.y);
    st.w = pack2(o1.z, o1.w);
    *(uint4*)&hb[(size_t)row * EMBn + lane * 8] = st;
  } else {
    int r = bid - 512;
    int hh = r & 7;
    if (tid < HSn) cs[tid] = cells[(size_t)r * HSn + tid];
    __syncthreads();
    for (int e = tid; e < EMBn; e += 256) {
      float acc = 0.f;
#pragma unroll 8
      for (int s2 = 0; s2 < HSn; ++s2)
        acc += cs[s2] * q_w[(size_t)(hh * HSn + s2) * EMBn + e];
      Pb[(size_t)r * EMBn + e] = f2bf(acc);
    }
    if (tid == 0) {
      float a = 0.f;
      for (int s2 = 0; s2 < HSn; ++s2) a += cs[s2] * q_b[hh * HSn + s2];
      pb[r] = a;
    }
  }
}

// ---------------------------------------------------------------------------
// MFMA GEMM core: C[r0+0..31][n0+0..63] (+= bias, *0.125 if BIAS) =
//   sum_k A[r][k]*Bt[n][k], K=512, all row strides 512 (bf16 A/Bt, f32 C).
// Block = 256 threads (4 waves, 2x2 wave grid of 16r x 32n tiles).
// LDS: A dbuf 2x[32][64], Bt dbuf 2x[64][64], XOR-swizzled (byte^=(row&7)<<4).
// ---------------------------------------------------------------------------
template <bool BIAS>
__device__ __forceinline__ void gemm_core(const u16* __restrict__ Ag,
                                          const u16* __restrict__ Bg,
                                          float* __restrict__ Cg,
                                          const float* __restrict__ pbv,
                                          int r0, int n0, int tid,
                                          u16* smem) {
  const int wave = tid >> 6, lane = tid & 63;
  const int srow = lane >> 3, sblk = lane & 7;
  const u16* gsrc0;
  const u16* gsrc1;
  const u16* gsrc2;
  unsigned lofs0, lofs1, lofs2, lstep0, lstep1, lstep2;
  {
    int id0 = wave * 3;
#pragma unroll
    for (int q = 0; q < 3; ++q) {
      int id = id0 + q;
      const u16* g;
      unsigned lo, ls;
      if (id < 4) {
        int row = id * 8 + srow;
        g = Ag + (size_t)(r0 + row) * 512 + sblk * 8;
        lo = row * 64 + (((sblk * 16) ^ ((row & 7) << 4)) >> 1);
        ls = 2048;
      } else {
        int row = (id - 4) * 8 + srow;
        g = Bg + (size_t)(n0 + row) * 512 + sblk * 8;
        lo = 4096 + row * 64 + (((sblk * 16) ^ ((row & 7) << 4)) >> 1);
        ls = 4096;
      }
      if (q == 0) { gsrc0 = g; lofs0 = lo; lstep0 = ls; }
      else if (q == 1) { gsrc1 = g; lofs1 = lo; lstep1 = ls; }
      else { gsrc2 = g; lofs2 = lo; lstep2 = ls; }
    }
  }
  // prologue: stage chunk 0 into buffer 0
  uint4 rv0 = *(const uint4*)gsrc0;
  uint4 rv1 = *(const uint4*)gsrc1;
  uint4 rv2 = *(const uint4*)gsrc2;
  *(uint4*)&smem[lofs0] = rv0;
  *(uint4*)&smem[lofs1] = rv1;
  *(uint4*)&smem[lofs2] = rv2;
  __syncthreads();

  f32x4 acc0 = {0.f, 0.f, 0.f, 0.f};
  f32x4 acc1 = {0.f, 0.f, 0.f, 0.f};
  const int ra = (wave >> 1) * 16 + (lane & 15);
  const int nb = (wave & 1) * 32 + (lane & 15);
  const unsigned asw = (unsigned)((ra & 7) << 4);
  const unsigned bsw = (unsigned)((nb & 7) << 4);
  const unsigned kg = (unsigned)((lane >> 4) * 16);

#pragma unroll
  for (int c = 0; c < 8; ++c) {
    const int cur = c & 1;
    if (c < 7) {
      rv0 = *(const uint4*)(gsrc0 + (c + 1) * 64);
      rv1 = *(const uint4*)(gsrc1 + (c + 1) * 64);
      rv2 = *(const uint4*)(gsrc2 + (c + 1) * 64);
    }
    const char* Ab = (const char*)(smem + cur * 2048);
    const char* Bb = (const char*)(smem + 4096 + cur * 4096);
#pragma unroll
    for (int ks = 0; ks < 2; ++ks) {
      unsigned kb = ks * 64 + kg;
      bf16x8 a = *(const bf16x8*)(Ab + ra * 128 + (kb ^ asw));
      bf16x8 b0 = *(const bf16x8*)(Bb + nb * 128 + (kb ^ bsw));
      bf16x8 b1 = *(const bf16x8*)(Bb + (nb + 16) * 128 + (kb ^ bsw));
      acc0 = __builtin_amdgcn_mfma_f32_16x16x32_bf16(a, b0, acc0, 0, 0, 0);
      acc1 = __builtin_amdgcn_mfma_f32_16x16x32_bf16(a, b1, acc1, 0, 0, 0);
    }
    if (c < 7) {
      unsigned bo = (unsigned)(cur ^ 1);
      *(uint4*)&smem[lofs0 + bo * lstep0] = rv0;
      *(uint4*)&smem[lofs1 + bo * lstep1] = rv1;
      *(uint4*)&smem[lofs2 + bo * lstep2] = rv2;
    }
    __syncthreads();
  }

  const int rg = r0 + (wave >> 1) * 16 + ((lane >> 4) << 2);
  const int cg = n0 + (wave & 1) * 32 + (lane & 15);
#pragma unroll
  for (int j = 0; j < 4; ++j) {
    float v0 = acc0[j], v1 = acc1[j];
    if (BIAS) {
      float pv = pbv[rg + j];
      v0 = (v0 + pv) * 0.125f;
      v1 = (v1 + pv) * 0.125f;
    }
    Cg[(size_t)(rg + j) * 512 + cg] = v0;
    Cg[(size_t)(rg + j) * 512 + cg + 16] = v1;
  }
}

// ---------------------------------------------------------------------------
// K_B: blocks [0,256): score S = (P.h^T + pb)*0.125 ; blocks [256,512):
// transpose h -> ht[b][j][l] (bf16) for the gmat B-operand.
// ---------------------------------------------------------------------------
__global__ __launch_bounds__(256) void score_trans_kernel(
    const u16* __restrict__ hb, const u16* __restrict__ Pb,
    const float* __restrict__ pb, u16* __restrict__ htb,
    float* __restrict__ S) {
  __shared__ u16 smem[12288];
  int bid = blockIdx.x, tid = threadIdx.x;
  if (bid < 256) {
    int b = bid >> 6, rem = bid & 63;
    int r0 = (rem >> 3) * 32, l0 = (rem & 7) * 64;
    gemm_core<true>(Pb, hb + (size_t)b * Ln * EMBn, S + (size_t)b * Rn * Ln,
                    pb, r0, l0, tid, smem);
  } else {
    int t = bid - 256;
    int b = t >> 6, rem = t & 63;
    int l0 = (rem >> 3) * 64, j0 = (rem & 7) * 64;
    u16(*ts)[65] = (u16(*)[65])smem;
#pragma unroll
    for (int i = 0; i < 4; ++i) {
      int idx = tid + i * 256;
      int row = idx >> 4, c4 = (idx & 15) * 4;
      uint2 u = *(const uint2*)&hb[(size_t)(b * Ln + l0 + row) * EMBn + j0 + c4];
      ts[row][c4] = (u16)(u.x & 0xffffu);
      ts[row][c4 + 1] = (u16)(u.x >> 16);
      ts[row][c4 + 2] = (u16)(u.y & 0xffffu);
      ts[row][c4 + 3] = (u16)(u.y >> 16);
    }
    __syncthreads();
#pragma unroll
    for (int i = 0; i < 4; ++i) {
      int idx = tid + i * 256;
      int jr = idx >> 4, lc4 = (idx & 15) * 4;
      unsigned lo = (unsigned)ts[lc4][jr] | ((unsigned)ts[lc4 + 1][jr] << 16);
      unsigned hi = (unsigned)ts[lc4 + 2][jr] | ((unsigned)ts[lc4 + 3][jr] << 16);
      uint2 u;
      u.x = lo;
      u.y = hi;
      *(uint2*)&htb[(size_t)(b * EMBn + j0 + jr) * Ln + l0 + lc4] = u;
    }
  }
}

// K_C: softmax over l per (b,r) row, f32 in -> bf16 out. grid = B*R/4.
__global__ __launch_bounds__(256) void softmax_kernel(
    const float* __restrict__ S, u16* __restrict__ Wb) {
  int row = blockIdx.x * 4 + (threadIdx.x >> 6), lane = threadIdx.x & 63;
  const float* sr = S + (size_t)row * Ln + lane * 8;
  float4 a0 = *(const float4*)sr;
  float4 a1 = *(const float4*)(sr + 4);
  float mx = fmaxf(fmaxf(fmaxf(a0.x, a0.y), fmaxf(a0.z, a0.w)),
                   fmaxf(fmaxf(a1.x, a1.y), fmaxf(a1.z, a1.w)));
  mx = wave_max(mx);
  a0.x = __expf(a0.x - mx); a0.y = __expf(a0.y - mx);
  a0.z = __expf(a0.z - mx); a0.w = __expf(a0.w - mx);
  a1.x = __expf(a1.x - mx); a1.y = __expf(a1.y - mx);
  a1.z = __expf(a1.z - mx); a1.w = __expf(a1.w - mx);
  float s = a0.x + a0.y + a0.z + a0.w + a1.x + a1.y + a1.z + a1.w;
  s = wave_sum(s);
  float inv = 1.0f / s;
  uint4 st;
  st.x = pack2(a0.x * inv, a0.y * inv);
  st.y = pack2(a0.z * inv, a0.w * inv);
  st.z = pack2(a1.x * inv, a1.y * inv);
  st.w = pack2(a1.z * inv, a1.w * inv);
  *(uint4*)&Wb[(size_t)row * Ln + lane * 8] = st;
}

// K_D: G[b][r][j] = sum_l W[b][r][l] * ht[b][j][l]  (MFMA, B^T form)
__global__ __launch_bounds__(256) void gmat_kernel(const u16* __restrict__ Wb,
                                                   const u16* __restrict__ htb,
                                                   float* __restrict__ G) {
  __shared__ u16 smem[12288];
  int bid = blockIdx.x, tid = threadIdx.x;
  int b = bid >> 6, rem = bid & 63;
  int r0 = (rem >> 3) * 32, j0 = (rem & 7) * 64;
  gemm_core<false>(Wb + (size_t)b * Rn * Ln, htb + (size_t)b * EMBn * Ln,
                   G + (size_t)b * Rn * EMBn, nullptr, r0, j0, tid, smem);
}

// K_E: out[b,(m,h),s] = dot(v[m, h*64+s, :], G[b, r, :]) + vb[m, h*64+s]
__global__ __launch_bounds__(256) void out_kernel(
    const float* __restrict__ v, const float* __restrict__ vb,
    const float* __restrict__ G, float* __restrict__ out) {
  int bid = blockIdx.x;
  int m = bid >> 3, hh = bid & 7;
  __shared__ float Gs[Bn][EMBn];
  int tid = threadIdx.x;
#pragma unroll
  for (int i = 0; i < 8; ++i) {
    int idx = tid + i * 256;
    int bb = idx >> 9, e = idx & 511;
    Gs[bb][e] = G[((size_t)bb * Rn + bid) * EMBn + e];
  }
  __syncthreads();
  int wid = tid >> 6, lane = tid & 63;
  for (int rr = wid; rr < HSn; rr += 4) {
    const float* vr = v + ((size_t)m * EMBn + hh * HSn + rr) * EMBn + lane * 8;
    float4 v0 = *(const float4*)vr;
    float4 v1 = *(const float4*)(vr + 4);
    float acc[Bn];
#pragma unroll
    for (int bb = 0; bb < Bn; ++bb) {
      const float* gp = &Gs[bb][lane * 8];
      float4 g0 = *(const float4*)gp;
      float4 g1 = *(const float4*)(gp + 4);
      acc[bb] = v0.x * g0.x + v0.y * g0.y + v0.z * g0.z + v0.w * g0.w +
                v1.x * g1.x + v1.y * g1.y + v1.z * g1.z + v1.w * g1.w;
    }
#pragma unroll
    for (int off = 1; off < 64; off <<= 1) {
#pragma unroll
      for (int bb = 0; bb < Bn; ++bb) acc[bb] += __shfl_xor(acc[bb], off, 64);
    }
    if (lane == 0) {
      float vbv = vb[(size_t)m * EMBn + hh * HSn + rr];
#pragma unroll
      for (int bb = 0; bb < Bn; ++bb) {
        out[(((size_t)bb * Hn + hh) * Mn + m) * HSn + rr] = acc[bb] + vbv;
      }
    }
  }
}

extern "C" void kernel_launch(void* const* d_in, const int* in_sizes, int n_in,
                              void* d_out, int out_size, void* d_ws,
                              size_t ws_size, hipStream_t stream) {
  const float* x = (const float*)d_in[0];
  const float* cells = (const float*)d_in[1];
  const float* q_w = (const float*)d_in[2];
  const float* q_b = (const float*)d_in[3];
  const float* v = (const float*)d_in[4];
  const float* vb = (const float*)d_in[5];
  const float* ln_g = (const float*)d_in[6];
  const float* ln_b = (const float*)d_in[7];
  float* out = (float*)d_out;

  u16* hb = (u16*)d_ws;                            // B*L*EMB bf16 = 2 MB
  u16* htb = hb + (size_t)Bn * Ln * EMBn;          // 2 MB
  u16* Pb = htb + (size_t)Bn * Ln * EMBn;          // R*EMB bf16 = 256 KB
  u16* Wb = Pb + (size_t)Rn * EMBn;                // B*R*L bf16 = 1 MB
  float* pb = (float*)(Wb + (size_t)Bn * Rn * Ln); // 1 KB
  float* S = pb + Rn;                              // B*R*L f32 = 2 MB
  float* G = S + (size_t)Bn * Rn * Ln;             // B*R*EMB f32 = 2 MB

  ln_pproj_kernel<<<768, 256, 0, stream>>>(x, ln_g, ln_b, cells, q_w, q_b, hb,
                                           Pb, pb);
  score_trans_kernel<<<512, 256, 0, stream>>>(hb, Pb, pb, htb, S);
  softmax_kernel<<<Bn * Rn / 4, 256, 0, stream>>>(S, Wb);
  gmat_kernel<<<256, 256, 0, stream>>>(Wb, htb, G);
  out_kernel<<<Rn, 256, 0, stream>>>(v, vb, G, out);
}

// Round 3
// 38.389 us; speedup vs baseline: 2.4823x; 1.1222x over previous
//
#include <hip/hip_runtime.h>

typedef unsigned short u16;
typedef float f32x4 __attribute__((ext_vector_type(4)));
typedef short bf16x8 __attribute__((ext_vector_type(8)));

constexpr int Bn = 4, Ln = 512, Mn = 32, EMBn = 512, Hn = 8, HSn = 64;
constexpr int Rn = Mn * Hn; // 256

__device__ __forceinline__ float wave_sum(float v) {
#pragma unroll
  for (int off = 1; off < 64; off <<= 1) v += __shfl_xor(v, off, 64);
  return v;
}
__device__ __forceinline__ float wave_max(float v) {
#pragma unroll
  for (int off = 1; off < 64; off <<= 1) v = fmaxf(v, __shfl_xor(v, off, 64));
  return v;
}
__device__ __forceinline__ u16 f2bf(float f) {
  unsigned u = __float_as_uint(f);
  unsigned r = (u + 0x7FFFu + ((u >> 16) & 1u)) >> 16;
  return (u16)r;
}
__device__ __forceinline__ unsigned pack2(float a, float b) {
  return (unsigned)f2bf(a) | ((unsigned)f2bf(b) << 16);
}

// ---------------------------------------------------------------------------
// K_A: blocks [0,512): LayerNorm -> h_bf16. blocks [512,768): P = cells*q_w.
// ---------------------------------------------------------------------------
__global__ __launch_bounds__(256) void ln_pproj_kernel(
    const float* __restrict__ x, const float* __restrict__ gam,
    const float* __restrict__ bet, const float* __restrict__ cells,
    const float* __restrict__ q_w, const float* __restrict__ q_b,
    u16* __restrict__ hb, u16* __restrict__ Pb, float* __restrict__ pb) {
  int bid = blockIdx.x, tid = threadIdx.x;
  __shared__ float cs[HSn];
  if (bid < 512) {
    int row = bid * 4 + (tid >> 6), lane = tid & 63;
    const float* xr = x + (size_t)row * EMBn + lane * 8;
    float4 a0 = *(const float4*)xr;
    float4 a1 = *(const float4*)(xr + 4);
    float s = a0.x + a0.y + a0.z + a0.w + a1.x + a1.y + a1.z + a1.w;
    float ss = a0.x * a0.x + a0.y * a0.y + a0.z * a0.z + a0.w * a0.w +
               a1.x * a1.x + a1.y * a1.y + a1.z * a1.z + a1.w * a1.w;
    s = wave_sum(s);
    ss = wave_sum(ss);
    float mu = s * (1.0f / EMBn);
    float var = ss * (1.0f / EMBn) - mu * mu;
    float rstd = rsqrtf(var + 1e-5f);
    const float* gp = gam + lane * 8;
    const float* bp = bet + lane * 8;
    float4 g0 = *(const float4*)gp, g1 = *(const float4*)(gp + 4);
    float4 b0 = *(const float4*)bp, b1 = *(const float4*)(bp + 4);
    float4 o0, o1;
    o0.x = (a0.x - mu) * rstd * g0.x + b0.x;
    o0.y = (a0.y - mu) * rstd * g0.y + b0.y;
    o0.z = (a0.z - mu) * rstd * g0.z + b0.z;
    o0.w = (a0.w - mu) * rstd * g0.w + b0.w;
    o1.x = (a1.x - mu) * rstd * g1.x + b1.x;
    o1.y = (a1.y - mu) * rstd * g1.y + b1.y;
    o1.z = (a1.z - mu) * rstd * g1.z + b1.z;
    o1.w = (a1.w - mu) * rstd * g1.w + b1.w;
    uint4 st;
    st.x = pack2(o0.x, o0.y);
    st.y = pack2(o0.z, o0.w);
    st.z = pack2(o1.x, o1.y);
    st.w = pack2(o1.z, o1.w);
    *(uint4*)&hb[(size_t)row * EMBn + lane * 8] = st;
  } else {
    int r = bid - 512;
    int hh = r & 7;
    if (tid < HSn) cs[tid] = cells[(size_t)r * HSn + tid];
    __syncthreads();
    for (int e = tid; e < EMBn; e += 256) {
      float acc = 0.f;
#pragma unroll 8
      for (int s2 = 0; s2 < HSn; ++s2)
        acc += cs[s2] * q_w[(size_t)(hh * HSn + s2) * EMBn + e];
      Pb[(size_t)r * EMBn + e] = f2bf(acc);
    }
    if (tid == 0) {
      float a = 0.f;
      for (int s2 = 0; s2 < HSn; ++s2) a += cs[s2] * q_b[hh * HSn + s2];
      pb[r] = a;
    }
  }
}

// ---------------------------------------------------------------------------
// MFMA GEMM core (used by score): C tile 32x64 = A[32xK] * B^T[64xK], K=512.
// ---------------------------------------------------------------------------
template <bool BIAS>
__device__ __forceinline__ void gemm_core(const u16* __restrict__ Ag,
                                          const u16* __restrict__ Bg,
                                          float* __restrict__ Cg,
                                          const float* __restrict__ pbv,
                                          int r0, int n0, int tid,
                                          u16* smem) {
  const int wave = tid >> 6, lane = tid & 63;
  const int srow = lane >> 3, sblk = lane & 7;
  const u16* gsrc0;
  const u16* gsrc1;
  const u16* gsrc2;
  unsigned lofs0, lofs1, lofs2, lstep0, lstep1, lstep2;
  {
    int id0 = wave * 3;
#pragma unroll
    for (int q = 0; q < 3; ++q) {
      int id = id0 + q;
      const u16* g;
      unsigned lo, ls;
      if (id < 4) {
        int row = id * 8 + srow;
        g = Ag + (size_t)(r0 + row) * 512 + sblk * 8;
        lo = row * 64 + (((sblk * 16) ^ ((row & 7) << 4)) >> 1);
        ls = 2048;
      } else {
        int row = (id - 4) * 8 + srow;
        g = Bg + (size_t)(n0 + row) * 512 + sblk * 8;
        lo = 4096 + row * 64 + (((sblk * 16) ^ ((row & 7) << 4)) >> 1);
        ls = 4096;
      }
      if (q == 0) { gsrc0 = g; lofs0 = lo; lstep0 = ls; }
      else if (q == 1) { gsrc1 = g; lofs1 = lo; lstep1 = ls; }
      else { gsrc2 = g; lofs2 = lo; lstep2 = ls; }
    }
  }
  uint4 rv0 = *(const uint4*)gsrc0;
  uint4 rv1 = *(const uint4*)gsrc1;
  uint4 rv2 = *(const uint4*)gsrc2;
  *(uint4*)&smem[lofs0] = rv0;
  *(uint4*)&smem[lofs1] = rv1;
  *(uint4*)&smem[lofs2] = rv2;
  __syncthreads();

  f32x4 acc0 = {0.f, 0.f, 0.f, 0.f};
  f32x4 acc1 = {0.f, 0.f, 0.f, 0.f};
  const int ra = (wave >> 1) * 16 + (lane & 15);
  const int nb = (wave & 1) * 32 + (lane & 15);
  const unsigned asw = (unsigned)((ra & 7) << 4);
  const unsigned bsw = (unsigned)((nb & 7) << 4);
  const unsigned kg = (unsigned)((lane >> 4) * 16);

#pragma unroll
  for (int c = 0; c < 8; ++c) {
    const int cur = c & 1;
    if (c < 7) {
      rv0 = *(const uint4*)(gsrc0 + (c + 1) * 64);
      rv1 = *(const uint4*)(gsrc1 + (c + 1) * 64);
      rv2 = *(const uint4*)(gsrc2 + (c + 1) * 64);
    }
    const char* Ab = (const char*)(smem + cur * 2048);
    const char* Bb = (const char*)(smem + 4096 + cur * 4096);
#pragma unroll
    for (int ks = 0; ks < 2; ++ks) {
      unsigned kb = ks * 64 + kg;
      bf16x8 a = *(const bf16x8*)(Ab + ra * 128 + (kb ^ asw));
      bf16x8 b0 = *(const bf16x8*)(Bb + nb * 128 + (kb ^ bsw));
      bf16x8 b1 = *(const bf16x8*)(Bb + (nb + 16) * 128 + (kb ^ bsw));
      acc0 = __builtin_amdgcn_mfma_f32_16x16x32_bf16(a, b0, acc0, 0, 0, 0);
      acc1 = __builtin_amdgcn_mfma_f32_16x16x32_bf16(a, b1, acc1, 0, 0, 0);
    }
    if (c < 7) {
      unsigned bo = (unsigned)(cur ^ 1);
      *(uint4*)&smem[lofs0 + bo * lstep0] = rv0;
      *(uint4*)&smem[lofs1 + bo * lstep1] = rv1;
      *(uint4*)&smem[lofs2 + bo * lstep2] = rv2;
    }
    __syncthreads();
  }

  const int rg = r0 + (wave >> 1) * 16 + ((lane >> 4) << 2);
  const int cg = n0 + (wave & 1) * 32 + (lane & 15);
#pragma unroll
  for (int j = 0; j < 4; ++j) {
    float v0 = acc0[j], v1 = acc1[j];
    if (BIAS) {
      float pv = pbv[rg + j];
      v0 = (v0 + pv) * 0.125f;
      v1 = (v1 + pv) * 0.125f;
    }
    Cg[(size_t)(rg + j) * 512 + cg] = v0;
    Cg[(size_t)(rg + j) * 512 + cg + 16] = v1;
  }
}

// ---------------------------------------------------------------------------
// K_B: blocks [0,256): score S = (P.h^T + pb)*0.125 ; blocks [256,512):
// transpose h -> ht[b][j][l] (bf16) for the gmat B-operand.
// ---------------------------------------------------------------------------
__global__ __launch_bounds__(256) void score_trans_kernel(
    const u16* __restrict__ hb, const u16* __restrict__ Pb,
    const float* __restrict__ pb, u16* __restrict__ htb,
    float* __restrict__ S) {
  __shared__ u16 smem[12288];
  int bid = blockIdx.x, tid = threadIdx.x;
  if (bid < 256) {
    int b = bid >> 6, rem = bid & 63;
    int r0 = (rem >> 3) * 32, l0 = (rem & 7) * 64;
    gemm_core<true>(Pb, hb + (size_t)b * Ln * EMBn, S + (size_t)b * Rn * Ln,
                    pb, r0, l0, tid, smem);
  } else {
    int t = bid - 256;
    int b = t >> 6, rem = t & 63;
    int l0 = (rem >> 3) * 64, j0 = (rem & 7) * 64;
    u16(*ts)[65] = (u16(*)[65])smem;
#pragma unroll
    for (int i = 0; i < 4; ++i) {
      int idx = tid + i * 256;
      int row = idx >> 4, c4 = (idx & 15) * 4;
      uint2 u = *(const uint2*)&hb[(size_t)(b * Ln + l0 + row) * EMBn + j0 + c4];
      ts[row][c4] = (u16)(u.x & 0xffffu);
      ts[row][c4 + 1] = (u16)(u.x >> 16);
      ts[row][c4 + 2] = (u16)(u.y & 0xffffu);
      ts[row][c4 + 3] = (u16)(u.y >> 16);
    }
    __syncthreads();
#pragma unroll
    for (int i = 0; i < 4; ++i) {
      int idx = tid + i * 256;
      int jr = idx >> 4, lc4 = (idx & 15) * 4;
      unsigned lo = (unsigned)ts[lc4][jr] | ((unsigned)ts[lc4 + 1][jr] << 16);
      unsigned hi = (unsigned)ts[lc4 + 2][jr] | ((unsigned)ts[lc4 + 3][jr] << 16);
      uint2 u;
      u.x = lo;
      u.y = hi;
      *(uint2*)&htb[(size_t)(b * EMBn + j0 + jr) * Ln + l0 + lc4] = u;
    }
  }
}

// ---------------------------------------------------------------------------
// K_C: fused softmax + gmat. Block (b, r0 32-row group, j0 64-col tile).
// Softmax of S[b][r0..r0+32][:] -> LDS W-tile (bf16, XOR-swizzled, full K).
// Then G[b][r0..+32][j0..+64] = W . htb^T (MFMA, B double-buffered).
// ---------------------------------------------------------------------------
__global__ __launch_bounds__(256) void gmat_sm_kernel(
    const float* __restrict__ S, const u16* __restrict__ htb,
    float* __restrict__ G) {
  __shared__ u16 Wlds[32 * 512];   // 32 KiB, row stride 1024 B, swizzled
  __shared__ u16 Bl[2][64 * 64];   // 2 x 8 KiB dbuf
  int bid = blockIdx.x, tid = threadIdx.x;
  int b = bid >> 6, rem = bid & 63;
  int r0 = (rem >> 3) * 32, j0 = (rem & 7) * 64;

  // ---- Phase A: softmax. 8 threads per row; 64 values per thread in regs.
  {
    int row = tid >> 3, sub = tid & 7;
    const float* sp = S + ((size_t)b * Rn + r0 + row) * Ln + sub * 64;
    float4 vv[16];
#pragma unroll
    for (int i = 0; i < 16; ++i) vv[i] = *(const float4*)(sp + i * 4);
    float mx = -1e30f;
#pragma unroll
    for (int i = 0; i < 16; ++i)
      mx = fmaxf(mx, fmaxf(fmaxf(vv[i].x, vv[i].y), fmaxf(vv[i].z, vv[i].w)));
#pragma unroll
    for (int off = 1; off < 8; off <<= 1) mx = fmaxf(mx, __shfl_xor(mx, off, 64));
    float sum = 0.f;
#pragma unroll
    for (int i = 0; i < 16; ++i) {
      vv[i].x = __expf(vv[i].x - mx);
      vv[i].y = __expf(vv[i].y - mx);
      vv[i].z = __expf(vv[i].z - mx);
      vv[i].w = __expf(vv[i].w - mx);
      sum += vv[i].x + vv[i].y + vv[i].z + vv[i].w;
    }
#pragma unroll
    for (int off = 1; off < 8; off <<= 1) sum += __shfl_xor(sum, off, 64);
    float inv = 1.0f / sum;
    unsigned swz = (unsigned)((row & 7) << 4);
    char* wbase = (char*)Wlds + row * 1024;
#pragma unroll
    for (int q = 0; q < 8; ++q) {
      uint4 st;
      st.x = pack2(vv[2 * q].x * inv, vv[2 * q].y * inv);
      st.y = pack2(vv[2 * q].z * inv, vv[2 * q].w * inv);
      st.z = pack2(vv[2 * q + 1].x * inv, vv[2 * q + 1].y * inv);
      st.w = pack2(vv[2 * q + 1].z * inv, vv[2 * q + 1].w * inv);
      *(uint4*)(wbase + (((unsigned)(sub * 128 + q * 16)) ^ swz)) = st;
    }
  }

  // ---- Phase B: GEMM. B-staging: thread -> 2 x 16B units.
  const int wave = tid >> 6, lane = tid & 63;
  int brow = tid >> 2, bks = (tid & 3) * 2;
  const u16* bg = htb + ((size_t)b * EMBn + j0 + brow) * Ln + bks * 8;
  unsigned bswz = (unsigned)((brow & 7) << 4);
  unsigned bofs0 = brow * 128 + (((unsigned)(bks * 16)) ^ bswz);
  unsigned bofs1 = brow * 128 + (((unsigned)(bks * 16 + 16)) ^ bswz);

  uint4 rv0 = *(const uint4*)bg;
  uint4 rv1 = *(const uint4*)(bg + 8);
  *(uint4*)((char*)Bl[0] + bofs0) = rv0;
  *(uint4*)((char*)Bl[0] + bofs1) = rv1;
  __syncthreads();

  f32x4 acc0 = {0.f, 0.f, 0.f, 0.f};
  f32x4 acc1 = {0.f, 0.f, 0.f, 0.f};
  const int ra = (wave >> 1) * 16 + (lane & 15);
  const int nb = (wave & 1) * 32 + (lane & 15);
  const unsigned asw = (unsigned)((ra & 7) << 4);
  const unsigned bsw = (unsigned)((nb & 7) << 4);
  const unsigned kg = (unsigned)((lane >> 4) * 16);
  const char* Abase = (const char*)Wlds + ra * 1024;

#pragma unroll
  for (int c = 0; c < 8; ++c) {
    const int cur = c & 1;
    if (c < 7) {
      rv0 = *(const uint4*)(bg + (c + 1) * 64);
      rv1 = *(const uint4*)(bg + (c + 1) * 64 + 8);
    }
    const char* Bb = (const char*)Bl[cur];
#pragma unroll
    for (int ks = 0; ks < 2; ++ks) {
      unsigned kbA = (unsigned)(c * 128 + ks * 64) + kg;
      unsigned kbB = (unsigned)(ks * 64) + kg;
      bf16x8 a = *(const bf16x8*)(Abase + (kbA ^ asw));
      bf16x8 b0 = *(const bf16x8*)(Bb + nb * 128 + (kbB ^ bsw));
      bf16x8 b1 = *(const bf16x8*)(Bb + (nb + 16) * 128 + (kbB ^ bsw));
      acc0 = __builtin_amdgcn_mfma_f32_16x16x32_bf16(a, b0, acc0, 0, 0, 0);
      acc1 = __builtin_amdgcn_mfma_f32_16x16x32_bf16(a, b1, acc1, 0, 0, 0);
    }
    if (c < 7) {
      char* Bo = (char*)Bl[cur ^ 1];
      *(uint4*)(Bo + bofs0) = rv0;
      *(uint4*)(Bo + bofs1) = rv1;
    }
    __syncthreads();
  }

  const int rg = r0 + (wave >> 1) * 16 + ((lane >> 4) << 2);
  const int cg = j0 + (wave & 1) * 32 + (lane & 15);
#pragma unroll
  for (int j = 0; j < 4; ++j) {
    G[((size_t)b * Rn + rg + j) * EMBn + cg] = acc0[j];
    G[((size_t)b * Rn + rg + j) * EMBn + cg + 16] = acc1[j];
  }
}

// ---------------------------------------------------------------------------
// K_D: out[b,(m,h),s] = dot(v[m, h*64+s, :], G[b, r, :]) + vb[m, h*64+s]
// grid = 1024 (m x hh x 4 s-chunks), 4 waves; wave handles 4 rows.
// ---------------------------------------------------------------------------
__global__ __launch_bounds__(256) void out_kernel(
    const float* __restrict__ v, const float* __restrict__ vb,
    const float* __restrict__ G, float* __restrict__ out) {
  int bid = blockIdx.x;
  int sc = bid & 3, hh = (bid >> 2) & 7, m = bid >> 5;
  int r = m * Hn + hh;
  __shared__ float Gs[Bn][EMBn]; // 8 KiB
  int tid = threadIdx.x;
#pragma unroll
  for (int i = 0; i < 2; ++i) {
    int idx4 = tid + i * 256;
    int bb = idx4 >> 7, e4 = (idx4 & 127) << 2;
    *(float4*)&Gs[bb][e4] = *(const float4*)&G[((size_t)bb * Rn + r) * EMBn + e4];
  }
  __syncthreads();
  int wid = tid >> 6, lane = tid & 63;
#pragma unroll
  for (int i = 0; i < 4; ++i) {
    int rr = sc * 16 + wid * 4 + i;
    const float* vr = v + ((size_t)m * EMBn + hh * HSn + rr) * EMBn + lane * 8;
    float4 v0 = *(const float4*)vr;
    float4 v1 = *(const float4*)(vr + 4);
    float acc[Bn];
#pragma unroll
    for (int bb = 0; bb < Bn; ++bb) {
      const float* gp = &Gs[bb][lane * 8];
      float4 g0 = *(const float4*)gp;
      float4 g1 = *(const float4*)(gp + 4);
      acc[bb] = v0.x * g0.x + v0.y * g0.y + v0.z * g0.z + v0.w * g0.w +
                v1.x * g1.x + v1.y * g1.y + v1.z * g1.z + v1.w * g1.w;
    }
#pragma unroll
    for (int off = 1; off < 64; off <<= 1) {
#pragma unroll
      for (int bb = 0; bb < Bn; ++bb) acc[bb] += __shfl_xor(acc[bb], off, 64);
    }
    if (lane == 0) {
      float vbv = vb[(size_t)m * EMBn + hh * HSn + rr];
#pragma unroll
      for (int bb = 0; bb < Bn; ++bb) {
        out[(((size_t)bb * Hn + hh) * Mn + m) * HSn + rr] = acc[bb] + vbv;
      }
    }
  }
}

extern "C" void kernel_launch(void* const* d_in, const int* in_sizes, int n_in,
                              void* d_out, int out_size, void* d_ws,
                              size_t ws_size, hipStream_t stream) {
  const float* x = (const float*)d_in[0];
  const float* cells = (const float*)d_in[1];
  const float* q_w = (const float*)d_in[2];
  const float* q_b = (const float*)d_in[3];
  const float* v = (const float*)d_in[4];
  const float* vb = (const float*)d_in[5];
  const float* ln_g = (const float*)d_in[6];
  const float* ln_b = (const float*)d_in[7];
  float* out = (float*)d_out;

  u16* hb = (u16*)d_ws;                            // B*L*EMB bf16 = 2 MB
  u16* htb = hb + (size_t)Bn * Ln * EMBn;          // 2 MB
  u16* Pb = htb + (size_t)Bn * Ln * EMBn;          // 256 KB
  float* pb = (float*)(Pb + (size_t)Rn * EMBn);    // 1 KB
  float* S = pb + Rn;                              // B*R*L f32 = 2 MB
  float* G = S + (size_t)Bn * Rn * Ln;             // B*R*EMB f32 = 2 MB

  ln_pproj_kernel<<<768, 256, 0, stream>>>(x, ln_g, ln_b, cells, q_w, q_b, hb,
                                           Pb, pb);
  score_trans_kernel<<<512, 256, 0, stream>>>(hb, Pb, pb, htb, S);
  gmat_sm_kernel<<<256, 256, 0, stream>>>(S, htb, G);
  out_kernel<<<1024, 256, 0, stream>>>(v, vb, G, out);
}